// Round 19
// baseline (586.369 us; speedup 1.0000x reference)
//
#include <hip/hip_runtime.h>
#include <hip/hip_bf16.h>
#include <math.h>

#define H 256
#define F 16
#define MUL 16
#define NB 8
#define LROW 296   // As row stride (elems): 148 dwords == 20 mod 32 -> 2-way (free)
#define YROW 264   // Ys row stride (elems): 132 dwords == 4 mod 32  -> 2-way (free)

typedef short bf16x8 __attribute__((ext_vector_type(8)));
typedef short bf16x4 __attribute__((ext_vector_type(4)));
typedef float f32x4 __attribute__((ext_vector_type(4)));
#define MFMA_B16(a, b, c) __builtin_amdgcn_mfma_f32_16x16x32_bf16(a, b, c, 0, 0, 0)

__device__ __forceinline__ float bf2f(__hip_bfloat16 x) { return __bfloat162float(x); }
// silu via v_rcp (no -ffast-math: plain '/' emits the full div-fixup chain)
__device__ __forceinline__ float silu(float x)
{
    return x * __builtin_amdgcn_rcpf(1.f + __expf(-x));
}
__device__ __forceinline__ short f2bs(float x)
{
    __hip_bfloat16 h = __float2bfloat16(x);
    short s; __builtin_memcpy(&s, &h, 2); return s;
}
__device__ __forceinline__ float bs2f(short s)
{
    __hip_bfloat16 h; __builtin_memcpy(&h, &s, 2); return __bfloat162float(h);
}
__device__ __forceinline__ float rawld(const void* p, int flag, size_t o)
{
    return flag ? ((const float*)p)[o] : bf2f(((const __hip_bfloat16*)p)[o]);
}

// ---------------- dtype sniffer (also zeroes cnt: saves a memset launch)
__global__ __launch_bounds__(256) void k_sniff(const void* vec, int* flag,
                                               int* cnt, int N)
{
    __shared__ int bad;
    int tid = threadIdx.x;
    if (tid == 0) bad = 0;
    __syncthreads();
    const __hip_bfloat16* hp = (const __hip_bfloat16*)vec;
    for (int i = tid; i < 1024; i += 256) {
        float f = bf2f(hp[i]);
        if (!(isfinite(f) && fabsf(f) <= 1.0f)) bad = 1;
    }
    for (int i = tid; i < N; i += 256) cnt[i] = 0;
    __syncthreads();
    if (tid == 0) *flag = bad;
}

// ---------------- merged converter: 7 fp32-consumer inputs -> canonical fp32
// (weights are swizzled straight from raw input; also does the sender
//  histogram -- cnt zeroed by the preceding k_sniff dispatch)
struct ConvArgs {
    const void* src[7];
    float* dst[7];
    int cum[8];
};
__global__ __launch_bounds__(256) void k_conv_all(ConvArgs a, const int* __restrict__ flag,
                                                  const int* __restrict__ snd,
                                                  int* __restrict__ cnt, int E)
{
    int gid = blockIdx.x * 256 + threadIdx.x;
    if (gid < E) atomicAdd(&cnt[snd[gid]], 1);
    if (gid >= a.cum[7]) return;
    int k = 0;
    while (gid >= a.cum[k + 1]) k++;
    int i = gid - a.cum[k];
    a.dst[k][i] = rawld(a.src[k], *flag, i);
}

// ---------------- merged weight swizzle: RAW [K][N] -> bf16 frag-linear
// entry 9 is W_out special mode ([256][1] -> [256x16] col 0 only)
struct SwzArgs {
    const void* src[10];
    __hip_bfloat16* dst[10];
    int K[10], Nc[10], cum[11];
    size_t soff[10];
};
__global__ __launch_bounds__(256) void k_swz_all(SwzArgs a, const int* __restrict__ flag)
{
    int gid = blockIdx.x * 256 + threadIdx.x;
    if (gid >= a.cum[10]) return;
    int fl = *flag;
    int j = 0;
    while (gid >= a.cum[j + 1]) j++;
    int idx = gid - a.cum[j];
    int kk = idx & 31;
    int n = (idx >> 5) % a.Nc[j];
    int kt = idx / (32 * a.Nc[j]);
    int k = kt * 32 + kk;
    float v = 0.f;
    if (j == 9) {                       // W_out: [256][1], col 0 only
        if (n == 0 && k < a.K[j]) v = rawld(a.src[j], fl, a.soff[j] + k);
    } else if (k < a.K[j]) {
        v = rawld(a.src[j], fl, a.soff[j] + (size_t)k * a.Nc[j] + n);
    }
    a.dst[j][idx] = __float2bfloat16(v);
}

// ---------------- CSR build (hist folded into k_conv_all)
__global__ __launch_bounds__(1024) void k_scan(const int* __restrict__ cnt,
                                               int* __restrict__ off,
                                               int* __restrict__ cur, int N)
{
    __shared__ int sums[1024];
    int tid = threadIdx.x;
    int chunk = (N + 1023) / 1024;
    int base = tid * chunk;
    int s = 0;
    for (int i = 0; i < chunk; i++) { int idx = base + i; if (idx < N) s += cnt[idx]; }
    sums[tid] = s;
    __syncthreads();
    for (int d = 1; d < 1024; d <<= 1) {
        int v = (tid >= d) ? sums[tid - d] : 0;
        __syncthreads();
        sums[tid] += v;
        __syncthreads();
    }
    int run = (tid == 0) ? 0 : sums[tid - 1];
    for (int i = 0; i < chunk; i++) {
        int idx = base + i;
        if (idx < N) { off[idx] = run; cur[idx] = run; run += cnt[idx]; }
    }
    if (tid == 1023) off[N] = run;
}

__global__ __launch_bounds__(256) void k_cscatter(const int* __restrict__ snd,
                                                  int* __restrict__ cur,
                                                  int* __restrict__ eidx, int E)
{
    int e = blockIdx.x * 256 + threadIdx.x;
    if (e >= E) return;
    int p = atomicAdd(&cur[snd[e]], 1);
    eidx[p] = e;
}

// =====================================================================
// Tile kernels (operand-swapped): A-operand = weight frag, B-operand = x frag
// Block = 64 edges x 8 waves (512 thr); wave w owns outcol slice 32w..32w+31
// (4-row x 2-col per-wave tile: measured optimum). Dual LDS buffers
// (71680 B) -> 2 blocks/CU, 16 waves/CU (measured optimum). vv precomputed
// (r5). 2-kt cross-barrier weight prefetch (r12 optimum).
// r19: k_layer is PERSISTENT (512 blocks x 4 consecutive tiles): tile t+1's
// x/vv loads issue right after tile t's staging barrier and fly under
// ~15k cycles of GEMM work -> staging latency off the critical path.
// Weight prefetch regs (w1p/w2p/twp) are tile-invariant: hoisted out.
// =====================================================================

// ---------------- MFMA embed tile kernel with fused geometry prologue
__global__ __launch_bounds__(512, 4) void k_embed_mfma(
    const float* __restrict__ vec, const float* __restrict__ na,
    const int* __restrict__ snd, const int* __restrict__ rcv,
    const __hip_bfloat16* __restrict__ We0s, const float* __restrict__ be0,
    const __hip_bfloat16* __restrict__ We1s, const float* __restrict__ be1,
    const __hip_bfloat16* __restrict__ Wv0s, const __hip_bfloat16* __restrict__ Wlws0,
    float* __restrict__ ubuf, float* __restrict__ Ybuf,
    __hip_bfloat16* __restrict__ xb, float* __restrict__ abuf,
    float* __restrict__ wbuf)
{
    __shared__ __align__(16) __hip_bfloat16 As[64 * LROW];  // 37888 B
    __shared__ __align__(16) __hip_bfloat16 Ys[64 * YROW];  // 33792 B
    __shared__ float us[64];
    int tid = threadIdx.x;
    int w = tid >> 6, l = tid & 63;
    int lm = l & 15, lq = l >> 4;
    int eb = blockIdx.x * 64;

    // prefetch GEMM1 weights (both kts) BEFORE the staging barrier
    bf16x8 w0p[2][2];
#pragma unroll
    for (int kt = 0; kt < 2; kt++)
#pragma unroll
        for (int nt = 0; nt < 2; nt++)
            w0p[kt][nt] = *(const bf16x8*)(We0s + ((size_t)(kt * 256 + w * 32 + nt * 16 + lm) * 32 + lq * 8));

    // ---- fused geometry: features straight into As; u,Y to global ----
    {
        int el = tid & 63;
        int part = tid >> 6;
        int ge = eb + el;
        const float SQ2 = 1.41421356237309515f;
        const float PI = 3.14159265358979323846f;
        if (part == 0) {
            float vx = vec[3 * ge + 0], vy = vec[3 * ge + 1], vz = vec[3 * ge + 2];
            float d = sqrtf(vx * vx + vy * vy + vz * vz);
            float d3 = d * d * d;
            float d6 = d3 * d3, d7 = d6 * d, d8 = d7 * d;
            float u = 1.f - 28.f * d6 + 48.f * d7 - 21.f * d8;
            u = (d < 1.f) ? u : 0.f;
            ubuf[ge] = u;
            us[el] = u;
            float invd = __builtin_amdgcn_rcpf(d);
#pragma unroll
            for (int k = 1; k <= 4; k++)
                As[el * LROW + (k - 1)] = __float2bfloat16(SQ2 * __sinf((float)k * PI * d) * invd);
        } else if (part == 4) {
            float vx = vec[3 * ge + 0], vy = vec[3 * ge + 1], vz = vec[3 * ge + 2];
            float d = sqrtf(vx * vx + vy * vy + vz * vz);
            float invd = __builtin_amdgcn_rcpf(d);
#pragma unroll
            for (int k = 5; k <= 8; k++)
                As[el * LROW + (k - 1)] = __float2bfloat16(SQ2 * __sinf((float)k * PI * d) * invd);
        } else if (part == 5) {
#pragma unroll
            for (int j = 40; j < 64; j++) As[el * LROW + j] = __float2bfloat16(0.f);
        } else if (part == 1) {
            int s = snd[ge];
#pragma unroll
            for (int j = 0; j < 16; j++)
                As[el * LROW + 8 + j] = __float2bfloat16(na[(size_t)s * F + j]);
        } else if (part == 2) {
            int r = rcv[ge];
#pragma unroll
            for (int j = 0; j < 16; j++)
                As[el * LROW + 24 + j] = __float2bfloat16(na[(size_t)r * F + j]);
        } else if (part == 3) {
            float vx = vec[3 * ge + 0], vy = vec[3 * ge + 1], vz = vec[3 * ge + 2];
            float d = sqrtf(vx * vx + vy * vy + vz * vz);
            float invd = __builtin_amdgcn_rcpf(d);
            float x = vx * invd, y = vy * invd, z = vz * invd;
            const float s3 = 1.7320508075688772f;
            const float s5 = 2.2360679774997896f;
            const float s15 = 3.8729833462074170f;
            const float s7 = 2.6457513110645907f;
            const float c33 = 2.0916500663351889f;
            const float c32 = 10.246950765959598f;
            const float c31 = 1.6201851746019651f;
            float* Yp = Ybuf + (size_t)ge * 16;
            Yp[0] = 1.f;
            Yp[1] = s3 * x;  Yp[2] = s3 * y;  Yp[3] = s3 * z;
            Yp[4] = s15 * x * y;  Yp[5] = s15 * y * z;
            Yp[6] = 0.5f * s5 * (3.f * z * z - 1.f);
            Yp[7] = s15 * x * z;
            Yp[8] = 0.5f * s15 * (x * x - y * y);
            Yp[9] = c33 * y * (3.f * x * x - y * y);
            Yp[10] = c32 * x * y * z;
            Yp[11] = c31 * y * (5.f * z * z - 1.f);
            Yp[12] = 0.5f * s7 * (5.f * z * z * z - 3.f * z);
            Yp[13] = c31 * x * (5.f * z * z - 1.f);
            Yp[14] = 0.5f * c32 * z * (x * x - y * y);
            Yp[15] = c33 * x * (x * x - 3.f * y * y);
        }
    }
    __syncthreads();

    // GEMM1: [64x64] @ [64x256]  (weights preloaded); wave owns 32 cols
    f32x4 acc[4][2];
#pragma unroll
    for (int mt = 0; mt < 4; mt++)
#pragma unroll
        for (int nt = 0; nt < 2; nt++) acc[mt][nt] = (f32x4){0.f, 0.f, 0.f, 0.f};
#pragma unroll
    for (int kt = 0; kt < 2; kt++) {
#pragma unroll
        for (int mt = 0; mt < 4; mt++) {
            bf16x8 bx = *(const bf16x8*)(As + (mt * 16 + lm) * LROW + kt * 32 + lq * 8);
#pragma unroll
            for (int nt = 0; nt < 2; nt++) acc[mt][nt] = MFMA_B16(w0p[kt][nt], bx, acc[mt][nt]);
        }
    }
    // prefetch GEMM2 kt=0,1 before the Ys barrier
    bf16x8 w1p[2][2];
#pragma unroll
    for (int kt = 0; kt < 2; kt++)
#pragma unroll
        for (int nt = 0; nt < 2; nt++)
            w1p[kt][nt] = *(const bf16x8*)(We1s + ((size_t)(kt * 256 + w * 32 + nt * 16 + lm) * 32 + lq * 8));
    // y0 = silu(acc + b0) -> Ys (disjoint from As: no barrier before writes)
#pragma unroll
    for (int nt = 0; nt < 2; nt++) {
        int cb = w * 32 + nt * 16 + lq * 4;
        f32x4 bb = *(const f32x4*)(be0 + cb);
#pragma unroll
        for (int mt = 0; mt < 4; mt++) {
            int row = mt * 16 + lm;
            bf16x4 v = {f2bs(silu(acc[mt][nt][0] + bb[0])), f2bs(silu(acc[mt][nt][1] + bb[1])),
                        f2bs(silu(acc[mt][nt][2] + bb[2])), f2bs(silu(acc[mt][nt][3] + bb[3]))};
            *(bf16x4*)(Ys + row * YROW + cb) = v;
        }
    }
    __syncthreads();

    // GEMM2: [64x256] @ [256x256]
#pragma unroll
    for (int mt = 0; mt < 4; mt++)
#pragma unroll
        for (int nt = 0; nt < 2; nt++) acc[mt][nt] = (f32x4){0.f, 0.f, 0.f, 0.f};
#pragma unroll
    for (int kt = 0; kt < 8; kt++) {
        bf16x8 aw[2];
#pragma unroll
        for (int nt = 0; nt < 2; nt++)
            aw[nt] = (kt < 2) ? w1p[kt][nt]
                   : *(const bf16x8*)(We1s + ((size_t)(kt * 256 + w * 32 + nt * 16 + lm) * 32 + lq * 8));
#pragma unroll
        for (int mt = 0; mt < 4; mt++) {
            bf16x8 bx = *(const bf16x8*)(Ys + (mt * 16 + lm) * YROW + kt * 32 + lq * 8);
#pragma unroll
            for (int nt = 0; nt < 2; nt++) acc[mt][nt] = MFMA_B16(aw[nt], bx, acc[mt][nt]);
        }
    }
    // prefetch GEMM3 tail weights (2 kts) before epilogue barrier
    const __hip_bfloat16* tw = (w < 4) ? Wv0s : Wlws0;
    bf16x8 twp[2];
#pragma unroll
    for (int kt = 0; kt < 2; kt++)
        twp[kt] = *(const bf16x8*)(tw + ((size_t)(kt * 16 + lm) * 32 + lq * 8));
    // epilogue: x1 = silu(.)*u -> xb global (8B stores) and As
#pragma unroll
    for (int nt = 0; nt < 2; nt++) {
        int cb = w * 32 + nt * 16 + lq * 4;
        f32x4 bb = *(const f32x4*)(be1 + cb);
#pragma unroll
        for (int mt = 0; mt < 4; mt++) {
            int row = mt * 16 + lm;
            float uu = us[row];
            bf16x4 v = {f2bs(silu(acc[mt][nt][0] + bb[0]) * uu),
                        f2bs(silu(acc[mt][nt][1] + bb[1]) * uu),
                        f2bs(silu(acc[mt][nt][2] + bb[2]) * uu),
                        f2bs(silu(acc[mt][nt][3] + bb[3]) * uu)};
            *(bf16x4*)(As + row * LROW + cb) = v;
            *(bf16x4*)(xb + (size_t)(eb + row) * H + cb) = v;
        }
    }
    __syncthreads();

    // GEMM3: a = x@Wv0 (waves 0-3), w = x@Wlw0 (waves 4-7)
    if (w < 4) {
        f32x4 av = (f32x4){0.f, 0.f, 0.f, 0.f};
#pragma unroll
        for (int kt = 0; kt < 8; kt++) {
            bf16x8 bx = *(const bf16x8*)(As + (w * 16 + lm) * LROW + kt * 32 + lq * 8);
            bf16x8 a_v = (kt < 2) ? twp[kt]
                       : *(const bf16x8*)(Wv0s + ((size_t)(kt * 16 + lm) * 32 + lq * 8));
            av = MFMA_B16(a_v, bx, av);
        }
        *(f32x4*)(abuf + (size_t)(eb + w * 16 + lm) * 16 + lq * 4) = av;
    } else {
        int w2 = w - 4;
        f32x4 aw2 = (f32x4){0.f, 0.f, 0.f, 0.f};
#pragma unroll
        for (int kt = 0; kt < 8; kt++) {
            bf16x8 bx = *(const bf16x8*)(As + (w2 * 16 + lm) * LROW + kt * 32 + lq * 8);
            bf16x8 a_w = (kt < 2) ? twp[kt]
                       : *(const bf16x8*)(Wlws0 + ((size_t)(kt * 16 + lm) * 32 + lq * 8));
            aw2 = MFMA_B16(a_w, bx, aw2);
        }
        *(f32x4*)(wbuf + (size_t)(eb + w2 * 16 + lm) * 16 + lq * 4) = aw2;
    }
}

// ---------------- gather #1 (wave-per-node): wYn0 = inv*segsum(w ⊗ Y) AND
// vv0[e,m] = wYn0[s,m,0]*a[e,m].  Wave w owns node 4*bid+w with a PRIVATE
// LDS region; waves march chunk-rounds in lockstep (maxc uniform).
__global__ __launch_bounds__(256) void k_gather0(
    const int* __restrict__ off, const int* __restrict__ eidx,
    const float* __restrict__ wbuf, const float* __restrict__ Ybuf,
    const float* __restrict__ abuf,
    float* __restrict__ wYn0, __hip_bfloat16* __restrict__ vvbuf)
{
    __shared__ float ws[4][16][17];
    __shared__ float Ysh[4][16][17];
    __shared__ float w00s[4][16];
    int tid = threadIdx.x;
    int w = tid >> 6, l = tid & 63;
    int js = l >> 4, i = l & 15;
    int n0 = blockIdx.x * 4;
    int n = n0 + w;
    int beg = off[n], end = off[n + 1];
    int o0 = off[n0], o1 = off[n0 + 1], o2 = off[n0 + 2], o3 = off[n0 + 3], o4 = off[n0 + 4];
    int m01 = max(o1 - o0, o2 - o1), m23 = max(o3 - o2, o4 - o3);
    int maxc = (max(m01, m23) + 15) >> 4;   // uniform across block
    float acc[4] = {0.f, 0.f, 0.f, 0.f};
    for (int r = 0; r < maxc; r++) {
        int c = beg + r * 16;
        int ne = min(16, end - c);          // <=0 when this wave is done
        if (ne > 0) {
#pragma unroll
            for (int k = 0; k < 4; k++) {
                int j = js + 4 * k;
                if (j < ne) {
                    int e = eidx[c + j];
                    ws[w][j][i]  = wbuf[(size_t)e * 16 + i];
                    Ysh[w][j][i] = Ybuf[(size_t)e * 16 + i];
                }
            }
        }
        __syncthreads();
        if (ne > 0) {
            for (int j2 = 0; j2 < ne; j2++) {
                float yv = Ysh[w][j2][i];
#pragma unroll
                for (int k = 0; k < 4; k++)
                    acc[k] += ws[w][j2][js + 4 * k] * yv;
            }
        }
        __syncthreads();
    }
#pragma unroll
    for (int k = 0; k < 4; k++)
        wYn0[(size_t)n * 256 + (js + 4 * k) * 16 + i] = acc[k] * 0.25f;
    if (i == 0) {
#pragma unroll
        for (int k = 0; k < 4; k++) w00s[w][js + 4 * k] = acc[k] * 0.25f;
    }
    __syncthreads();
    // pass 2 (no barriers): vv0[e,i] = w00[i]*a[e,i]; 4 edge-slots per wave
    float w0i = w00s[w][i];
    for (int c = beg + js; c < end; c += 4) {
        int e = eidx[c];
        float a = abuf[(size_t)e * 16 + i];
        vvbuf[(size_t)e * 16 + i] = __float2bfloat16(w0i * a);
    }
}

// ---------------- gather #2 (wave-per-node): wYn1 (local only) AND vv1[e,m] =
// wYn1[s,m,0]*a[e,m]*sum_i wYn0[s,m,i]*Wlsh0[i,0]*Y[e,i].  Also zeroes nacc.
__global__ __launch_bounds__(256) void k_gather1(
    const int* __restrict__ off, const int* __restrict__ eidx,
    const float* __restrict__ wbuf, const float* __restrict__ Ybuf,
    const float* __restrict__ abuf,
    const float* __restrict__ wYn0, const float* __restrict__ Wlsh,
    __hip_bfloat16* __restrict__ vvbuf, float* __restrict__ nacc)
{
    __shared__ float ws[4][16][17];
    __shared__ float Ysh[4][16][17];
    __shared__ float qsh[4][16][17];
    __shared__ float w10s[4][16];
    int tid = threadIdx.x;
    int w = tid >> 6, l = tid & 63;
    int js = l >> 4, i = l & 15;
    int n0 = blockIdx.x * 4;
    int n = n0 + w;
    int beg = off[n], end = off[n + 1];
    if (tid < 4) nacc[n0 + tid] = 0.f;
    int o0 = off[n0], o1 = off[n0 + 1], o2 = off[n0 + 2], o3 = off[n0 + 3], o4 = off[n0 + 4];
    int m01 = max(o1 - o0, o2 - o1), m23 = max(o3 - o2, o4 - o3);
    int maxc = (max(m01, m23) + 15) >> 4;   // uniform across block
    float acc[4] = {0.f, 0.f, 0.f, 0.f};
    for (int r = 0; r < maxc; r++) {
        int c = beg + r * 16;
        int ne = min(16, end - c);
        if (ne > 0) {
#pragma unroll
            for (int k = 0; k < 4; k++) {
                int j = js + 4 * k;
                if (j < ne) {
                    int e = eidx[c + j];
                    ws[w][j][i]  = wbuf[(size_t)e * 16 + i];
                    Ysh[w][j][i] = Ybuf[(size_t)e * 16 + i];
                }
            }
        }
        __syncthreads();
        if (ne > 0) {
            for (int j2 = 0; j2 < ne; j2++) {
                float yv = Ysh[w][j2][i];
#pragma unroll
                for (int k = 0; k < 4; k++)
                    acc[k] += ws[w][j2][js + 4 * k] * yv;
            }
        }
        __syncthreads();
    }
    if (i == 0) {
#pragma unroll
        for (int k = 0; k < 4; k++) w10s[w][js + 4 * k] = acc[k] * 0.25f;
    }
    // qsh[w][m][i] = wYn0[n,m,i] * Wlsh0[i,0]
#pragma unroll
    for (int k = 0; k < 4; k++) {
        int m = js + 4 * k;
        qsh[w][m][i] = wYn0[(size_t)n * 256 + m * 16 + i] * Wlsh[i * 16];
    }
    __syncthreads();
    // pass 2 (no barriers)
    float w1i = w10s[w][i];
    for (int c = beg + js; c < end; c += 4) {
        int e = eidx[c];
        float a = abuf[(size_t)e * 16 + i];
        float t = 0.f;
#pragma unroll
        for (int j = 0; j < 4; j++) {
            f32x4 yv = *(const f32x4*)(Ybuf + (size_t)e * 16 + 4 * j);
            t += qsh[w][i][4 * j + 0] * yv[0] + qsh[w][i][4 * j + 1] * yv[1]
               + qsh[w][i][4 * j + 2] * yv[2] + qsh[w][i][4 * j + 3] * yv[3];
        }
        vvbuf[(size_t)e * 16 + i] = __float2bfloat16(w1i * a * t);
    }
}

// ---------------- MFMA layer tile kernel -- PERSISTENT: 512 blocks x 4
// consecutive tiles. Tile t+1's x/vv prefetched into registers right after
// tile t's staging barrier (in flight under the GEMMs); weight prefetch
// regs hoisted out of the loop (tile-invariant).
__global__ __launch_bounds__(512, 4) void k_layer_mfma(
    __hip_bfloat16* __restrict__ xb, const float* __restrict__ ubuf,
    const __hip_bfloat16* __restrict__ vvbuf, const int* __restrict__ rcv,
    const __hip_bfloat16* __restrict__ W1s, const float* __restrict__ b1,
    const __hip_bfloat16* __restrict__ W2s, const float* __restrict__ b2,
    const __hip_bfloat16* __restrict__ Wlwn, float* __restrict__ wbufn,
    const __hip_bfloat16* __restrict__ Wouts, float* __restrict__ nacc,
    int layer)
{
    __shared__ __align__(16) __hip_bfloat16 As[64 * LROW];  // x | vv | 0
    __shared__ __align__(16) __hip_bfloat16 Ys[64 * YROW];  // hidden
    int tid = threadIdx.x;
    int w = tid >> 6, l = tid & 63;
    int lm = l & 15, lq = l >> 4;
    int base = blockIdx.x * 4;      // 4 consecutive 64-edge tiles

    // static staging coords (per thread)
    int srow[4], skc[4];
#pragma unroll
    for (int i = 0; i < 4; i++) { int c = tid + 512 * i; srow[i] = c >> 5; skc[i] = c & 31; }
    int el = tid & 63;
    int mh = (tid >> 6) * 2;

    // tile-invariant weight prefetch (stays in regs across all 4 tiles)
    bf16x8 w1p[2][2], w2p[2][2], twp[2];
#pragma unroll
    for (int kt = 0; kt < 2; kt++)
#pragma unroll
        for (int nt = 0; nt < 2; nt++) {
            w1p[kt][nt] = *(const bf16x8*)(W1s + ((size_t)(kt * 256 + w * 32 + nt * 16 + lm) * 32 + lq * 8));
            w2p[kt][nt] = *(const bf16x8*)(W2s + ((size_t)(kt * 256 + w * 32 + nt * 16 + lm) * 32 + lq * 8));
        }
    const __hip_bfloat16* tw = (layer == 0) ? Wlwn : Wouts;
#pragma unroll
    for (int kt = 0; kt < 2; kt++)
        twp[kt] = *(const bf16x8*)(tw + ((size_t)(kt * 16 + lm) * 32 + lq * 8));

    // prefetch tile 0 x/vv into registers
    bf16x8 xs[4];
#pragma unroll
    for (int i = 0; i < 4; i++)
        xs[i] = *(const bf16x8*)(xb + (size_t)(base * 64 + srow[i]) * H + skc[i] * 8);
    unsigned int vvp = *(const unsigned int*)((const short*)vvbuf + (size_t)(base * 64 + el) * 16 + mh);

    for (int t = 0; t < 4; t++) {
        int eb = (base + t) * 64;
        // stage x tile from registers + vv word; zeros once (cols 272..288
        // are never overwritten afterwards)
#pragma unroll
        for (int i = 0; i < 4; i++)
            *(bf16x8*)(As + srow[i] * LROW + skc[i] * 8) = xs[i];
        *(unsigned int*)(As + el * LROW + 256 + mh) = vvp;
        if (t == 0 && tid < 64) {
#pragma unroll
            for (int j = 0; j < 16; j++) As[tid * LROW + 272 + j] = __float2bfloat16(0.f);
        }
        __syncthreads();

        // issue next tile's loads NOW -- they fly under this tile's GEMMs
        if (t < 3) {
            int ebn = (base + t + 1) * 64;
#pragma unroll
            for (int i = 0; i < 4; i++)
                xs[i] = *(const bf16x8*)(xb + (size_t)(ebn + srow[i]) * H + skc[i] * 8);
            vvp = *(const unsigned int*)((const short*)vvbuf + (size_t)(ebn + el) * 16 + mh);
        }

        float uu[4];
#pragma unroll
        for (int mt = 0; mt < 4; mt++) uu[mt] = ubuf[eb + mt * 16 + lm];

        // GEMM1: [64x288] @ [288x256]; wave owns 32 output cols
        f32x4 acc[4][2];
#pragma unroll
        for (int mt = 0; mt < 4; mt++)
#pragma unroll
            for (int nt = 0; nt < 2; nt++) acc[mt][nt] = (f32x4){0.f, 0.f, 0.f, 0.f};
#pragma unroll
        for (int kt = 0; kt < 9; kt++) {
            bf16x8 aw[2];
#pragma unroll
            for (int nt = 0; nt < 2; nt++)
                aw[nt] = (kt < 2) ? w1p[kt][nt]
                       : *(const bf16x8*)(W1s + ((size_t)(kt * 256 + w * 32 + nt * 16 + lm) * 32 + lq * 8));
#pragma unroll
            for (int mt = 0; mt < 4; mt++) {
                bf16x8 bx = *(const bf16x8*)(As + (mt * 16 + lm) * LROW + kt * 32 + lq * 8);
#pragma unroll
                for (int nt = 0; nt < 2; nt++) acc[mt][nt] = MFMA_B16(aw[nt], bx, acc[mt][nt]);
            }
        }
        // y1 = silu(acc + b1) -> Ys packed (disjoint from As)
#pragma unroll
        for (int nt = 0; nt < 2; nt++) {
            int cb = w * 32 + nt * 16 + lq * 4;
            f32x4 bb = *(const f32x4*)(b1 + cb);
#pragma unroll
            for (int mt = 0; mt < 4; mt++) {
                int row = mt * 16 + lm;
                bf16x4 v = {f2bs(silu(acc[mt][nt][0] + bb[0])), f2bs(silu(acc[mt][nt][1] + bb[1])),
                            f2bs(silu(acc[mt][nt][2] + bb[2])), f2bs(silu(acc[mt][nt][3] + bb[3]))};
                *(bf16x4*)(Ys + row * YROW + cb) = v;
            }
        }
        __syncthreads();

        // GEMM2: [64x256] @ [256x256]
#pragma unroll
        for (int mt = 0; mt < 4; mt++)
#pragma unroll
            for (int nt = 0; nt < 2; nt++) acc[mt][nt] = (f32x4){0.f, 0.f, 0.f, 0.f};
#pragma unroll
        for (int kt = 0; kt < 8; kt++) {
            bf16x8 aw[2];
#pragma unroll
            for (int nt = 0; nt < 2; nt++)
                aw[nt] = (kt < 2) ? w2p[kt][nt]
                       : *(const bf16x8*)(W2s + ((size_t)(kt * 256 + w * 32 + nt * 16 + lm) * 32 + lq * 8));
#pragma unroll
            for (int mt = 0; mt < 4; mt++) {
                bf16x8 bx = *(const bf16x8*)(Ys + (mt * 16 + lm) * YROW + kt * 32 + lq * 8);
#pragma unroll
                for (int nt = 0; nt < 2; nt++) acc[mt][nt] = MFMA_B16(aw[nt], bx, acc[mt][nt]);
            }
        }
        // epilogue: xnew = (x_old + u*silu(acc+b2))/sqrt2; x_old read b64
        // from As; same thread writes same cells (WAR-safe, no barrier).
        const float rs2 = 0.70710678118654752f;
#pragma unroll
        for (int nt = 0; nt < 2; nt++) {
            int cb = w * 32 + nt * 16 + lq * 4;
            f32x4 bb = *(const f32x4*)(b2 + cb);
#pragma unroll
            for (int mt = 0; mt < 4; mt++) {
                int row = mt * 16 + lm;
                bf16x4 xo = *(const bf16x4*)(As + row * LROW + cb);
                bf16x4 v;
#pragma unroll
                for (int r = 0; r < 4; r++) {
                    float xn = (bs2f(xo[r]) + uu[mt] * silu(acc[mt][nt][r] + bb[r])) * rs2;
                    v[r] = f2bs(xn);
                }
                *(bf16x4*)(As + row * LROW + cb) = v;
                if (layer == 0) *(bf16x4*)(xb + (size_t)(eb + row) * H + cb) = v;
            }
        }
        __syncthreads();

        if (layer == 0) {
            // wcomp: w = x_new @ Wlwn -- waves 0-3 own edges w*16..w*16+15
            if (w < 4) {
                f32x4 cw = (f32x4){0.f, 0.f, 0.f, 0.f};
#pragma unroll
                for (int kt = 0; kt < 8; kt++) {
                    bf16x8 bx = *(const bf16x8*)(As + (w * 16 + lm) * LROW + kt * 32 + lq * 8);
                    bf16x8 a = (kt < 2) ? twp[kt]
                             : *(const bf16x8*)(Wlwn + ((size_t)(kt * 16 + lm) * 32 + lq * 8));
                    cw = MFMA_B16(a, bx, cw);
                }
                *(f32x4*)(wbufn + (size_t)(eb + w * 16 + lm) * 16 + lq * 4) = cw;
            }
        } else {
            // out-proj: edge_out = (x_new @ W_out) * u -> atomicAdd nacc[rcv]
            if (w < 4) {
                f32x4 co = (f32x4){0.f, 0.f, 0.f, 0.f};
#pragma unroll
                for (int kt = 0; kt < 8; kt++) {
                    bf16x8 bx = *(const bf16x8*)(As + (w * 16 + lm) * LROW + kt * 32 + lq * 8);
                    bf16x8 a = (kt < 2) ? twp[kt]
                             : *(const bf16x8*)(Wouts + ((size_t)(kt * 16 + lm) * 32 + lq * 8));
                    co = MFMA_B16(a, bx, co);
                }
                if (lq == 0) {
                    int e = eb + w * 16 + lm;
                    atomicAdd(&nacc[rcv[e]], co[0] * ubuf[e]);
                }
            }
        }
        __syncthreads();   // all As reads done before next tile's staging
    }
}

__global__ __launch_bounds__(256) void k_final(
    const float* __restrict__ nacc, void* __restrict__ out, const int* __restrict__ flag,
    float inv, int N)
{
    int n = blockIdx.x * 256 + threadIdx.x;
    if (n >= N) return;
    float v = nacc[n] * inv;
    if (*flag) ((float*)out)[n] = v;
    else       ((__hip_bfloat16*)out)[n] = __float2bfloat16(v);
}

extern "C" void kernel_launch(void* const* d_in, const int* in_sizes, int n_in,
                              void* d_out, int out_size, void* d_ws, size_t ws_size,
                              hipStream_t stream)
{
    const int E = in_sizes[2];      // 131072
    const int N = in_sizes[0] / F;  // 8192
    (void)n_in; (void)ws_size; (void)out_size;

    char* wsb = (char*)d_ws;
    size_t off = 0;
    int* flag = (int*)wsb; off += 256;

    // canonical fp32 only for fp32-consumers: na, vec, be0, be1, Wlsh, bly1, bly2
    const int cidx[7] = {0, 1, 5, 7, 10, 12, 14};
    float* canon[7];
    for (int k = 0; k < 7; k++) {
        canon[k] = (float*)(wsb + off);
        off += (size_t)in_sizes[cidx[k]] * 4;
        off = (off + 255) & ~(size_t)255;
    }
    const float* naC   = canon[0];
    const float* vecC  = canon[1];
    const float* be0C  = canon[2];
    const float* be1C  = canon[3];
    const float* WlshC = canon[4];
    const float* bly1C = canon[5];
    const float* bly2C = canon[6];

    // swizzled bf16 weights
    __hip_bfloat16* We0s  = (__hip_bfloat16*)(wsb + off); off += 64 * 256 * 2;
    __hip_bfloat16* We1s  = (__hip_bfloat16*)(wsb + off); off += 256 * 256 * 2;
    __hip_bfloat16* Wv0s  = (__hip_bfloat16*)(wsb + off); off += 256 * 16 * 2;
    __hip_bfloat16* Wlws0 = (__hip_bfloat16*)(wsb + off); off += 256 * 16 * 2;
    __hip_bfloat16* Wlws1 = (__hip_bfloat16*)(wsb + off); off += 256 * 16 * 2;
    __hip_bfloat16* W1s0  = (__hip_bfloat16*)(wsb + off); off += 288 * 256 * 2;
    __hip_bfloat16* W1s1  = (__hip_bfloat16*)(wsb + off); off += 288 * 256 * 2;
    __hip_bfloat16* W2s0  = (__hip_bfloat16*)(wsb + off); off += 256 * 256 * 2;
    __hip_bfloat16* W2s1  = (__hip_bfloat16*)(wsb + off); off += 256 * 256 * 2;
    __hip_bfloat16* Wouts = (__hip_bfloat16*)(wsb + off); off += 256 * 16 * 2;
    off = (off + 255) & ~(size_t)255;

    __hip_bfloat16* xbuf = (__hip_bfloat16*)(wsb + off); off += (size_t)E * H * 2;
    float* wYn0 = (float*)(wsb + off); off += (size_t)N * H * 4;
    __hip_bfloat16* vvbuf = (__hip_bfloat16*)(wsb + off); off += (size_t)E * 16 * 2;
    float* ubuf = (float*)(wsb + off); off += (size_t)E * 4;
    float* Ybuf = (float*)(wsb + off); off += (size_t)E * 16 * 4;
    float* abuf = (float*)(wsb + off); off += (size_t)E * 16 * 4;
    float* wbuf = (float*)(wsb + off); off += (size_t)E * 16 * 4;
    float* nacc = (float*)(wsb + off); off += (size_t)N * 4;
    int* cnt  = (int*)(wsb + off); off += (size_t)N * 4;
    int* offb = (int*)(wsb + off); off += (size_t)(N + 1) * 4;
    int* cur  = (int*)(wsb + off); off += (size_t)N * 4;
    int* eidx = (int*)(wsb + off); off += (size_t)E * 4;

    const int* snd = (const int*)d_in[2];
    const int* rcv = (const int*)d_in[3];
    const float inv = 0.25f;
    const int nb64 = E / 64;

    // dtype sniff (+ cnt zeroing) + merged canonicalization (+ sender hist)
    k_sniff<<<1, 256, 0, stream>>>(d_in[1], flag, cnt, N);
    {
        ConvArgs ca;
        int c = 0;
        for (int k = 0; k < 7; k++) {
            ca.src[k] = d_in[cidx[k]];
            ca.dst[k] = canon[k];
            ca.cum[k] = c;
            c += in_sizes[cidx[k]];
        }
        ca.cum[7] = c;
        k_conv_all<<<(c + 255) / 256, 256, 0, stream>>>(ca, flag, snd, cnt, E);
    }

    // merged weight swizzles (direct from RAW input; entry 9 = W_out mode)
    {
        SwzArgs sa;
        const void* srcs[10] = {d_in[4], d_in[6], d_in[8], d_in[9], d_in[9],
                                d_in[11], d_in[11], d_in[13], d_in[13], d_in[15]};
        size_t soffs[10]     = {0, 0, 0, 0, 256 * 16,
                                0, 272 * 256, 0, 256 * 256, 0};
        __hip_bfloat16* dsts[10] = {We0s, We1s, Wv0s, Wlws0, Wlws1,
                                    W1s0, W1s1, W2s0, W2s1, Wouts};
        int Ks[10]    = {40, 256, 256, 256, 256, 272, 272, 256, 256, 256};
        int Ncs[10]   = {256, 256, 16, 16, 16, 256, 256, 256, 256, 16};
        int Kpads[10] = {64, 256, 256, 256, 256, 288, 288, 256, 256, 256};
        int c = 0;
        for (int j = 0; j < 10; j++) {
            sa.src[j] = srcs[j]; sa.dst[j] = dsts[j];
            sa.K[j] = Ks[j]; sa.Nc[j] = Ncs[j]; sa.soff[j] = soffs[j];
            sa.cum[j] = c;
            c += (Kpads[j] >> 5) * Ncs[j] * 32;
        }
        sa.cum[10] = c;
        k_swz_all<<<(c + 255) / 256, 256, 0, stream>>>(sa, flag);
    }

    // sender CSR (hist folded into conv)
    k_scan<<<1, 1024, 0, stream>>>(cnt, offb, cur, N);
    k_cscatter<<<(E + 255) / 256, 256, 0, stream>>>(snd, cur, eidx, E);

    // embed (fused geometry)
    k_embed_mfma<<<nb64, 512, 0, stream>>>(vecC, naC, snd, rcv,
                                           We0s, be0C, We1s, be1C, Wv0s, Wlws0,
                                           ubuf, Ybuf, xbuf, abuf, wbuf);

    // layer 0 (persistent: 512 blocks x 4 tiles)
    k_gather0<<<N / 4, 256, 0, stream>>>(offb, eidx, wbuf, Ybuf, abuf, wYn0, vvbuf);
    k_layer_mfma<<<nb64 / 4, 512, 0, stream>>>(xbuf, ubuf, vvbuf, rcv,
                                               W1s0, bly1C, W2s0, bly2C,
                                               Wlws1, wbuf,
                                               (const __hip_bfloat16*)nullptr, (float*)nullptr, 0);
    // layer 1 (persistent; gather1 emits vv1 + zeroes nacc; fused out-proj)
    k_gather1<<<N / 4, 256, 0, stream>>>(offb, eidx, wbuf, Ybuf, abuf, wYn0, WlshC,
                                         vvbuf, nacc);
    k_layer_mfma<<<nb64 / 4, 512, 0, stream>>>(xbuf, ubuf, vvbuf, rcv,
                                               W1s1, bly1C + H, W2s1, bly2C + H,
                                               (const __hip_bfloat16*)nullptr, (float*)nullptr,
                                               Wouts, nacc, 1);

    k_final<<<(N + 255) / 256, 256, 0, stream>>>(nacc, d_out, flag, inv, N);
}

// Round 20
// 332.602 us; speedup vs baseline: 1.7630x; 1.7630x over previous
//
#include <hip/hip_runtime.h>
#include <hip/hip_bf16.h>
#include <math.h>

#define H 256
#define F 16
#define MUL 16
#define NB 8
#define LROW 296   // As row stride (elems): 148 dwords == 20 mod 32 -> 2-way (free)
#define YROW 264   // Ys row stride (elems): 132 dwords == 4 mod 32  -> 2-way (free)

typedef short bf16x8 __attribute__((ext_vector_type(8)));
typedef short bf16x4 __attribute__((ext_vector_type(4)));
typedef float f32x4 __attribute__((ext_vector_type(4)));
#define MFMA_B16(a, b, c) __builtin_amdgcn_mfma_f32_16x16x32_bf16(a, b, c, 0, 0, 0)

__device__ __forceinline__ float bf2f(__hip_bfloat16 x) { return __bfloat162float(x); }
// silu via v_rcp (no -ffast-math: plain '/' emits the full div-fixup chain)
__device__ __forceinline__ float silu(float x)
{
    return x * __builtin_amdgcn_rcpf(1.f + __expf(-x));
}
__device__ __forceinline__ short f2bs(float x)
{
    __hip_bfloat16 h = __float2bfloat16(x);
    short s; __builtin_memcpy(&s, &h, 2); return s;
}
__device__ __forceinline__ float bs2f(short s)
{
    __hip_bfloat16 h; __builtin_memcpy(&h, &s, 2); return __bfloat162float(h);
}
__device__ __forceinline__ float rawld(const void* p, int flag, size_t o)
{
    return flag ? ((const float*)p)[o] : bf2f(((const __hip_bfloat16*)p)[o]);
}

// ---------------- dtype sniffer (also zeroes cnt: saves a memset launch)
__global__ __launch_bounds__(256) void k_sniff(const void* vec, int* flag,
                                               int* cnt, int N)
{
    __shared__ int bad;
    int tid = threadIdx.x;
    if (tid == 0) bad = 0;
    __syncthreads();
    const __hip_bfloat16* hp = (const __hip_bfloat16*)vec;
    for (int i = tid; i < 1024; i += 256) {
        float f = bf2f(hp[i]);
        if (!(isfinite(f) && fabsf(f) <= 1.0f)) bad = 1;
    }
    for (int i = tid; i < N; i += 256) cnt[i] = 0;
    __syncthreads();
    if (tid == 0) *flag = bad;
}

// ---------------- merged converter: 7 fp32-consumer inputs -> canonical fp32
// (weights are swizzled straight from raw input; also does the sender
//  histogram -- cnt zeroed by the preceding k_sniff dispatch)
struct ConvArgs {
    const void* src[7];
    float* dst[7];
    int cum[8];
};
__global__ __launch_bounds__(256) void k_conv_all(ConvArgs a, const int* __restrict__ flag,
                                                  const int* __restrict__ snd,
                                                  int* __restrict__ cnt, int E)
{
    int gid = blockIdx.x * 256 + threadIdx.x;
    if (gid < E) atomicAdd(&cnt[snd[gid]], 1);
    if (gid >= a.cum[7]) return;
    int k = 0;
    while (gid >= a.cum[k + 1]) k++;
    int i = gid - a.cum[k];
    a.dst[k][i] = rawld(a.src[k], *flag, i);
}

// ---------------- merged weight swizzle: RAW [K][N] -> bf16 frag-linear
// entry 9 is W_out special mode ([256][1] -> [256x16] col 0 only)
struct SwzArgs {
    const void* src[10];
    __hip_bfloat16* dst[10];
    int K[10], Nc[10], cum[11];
    size_t soff[10];
};
__global__ __launch_bounds__(256) void k_swz_all(SwzArgs a, const int* __restrict__ flag)
{
    int gid = blockIdx.x * 256 + threadIdx.x;
    if (gid >= a.cum[10]) return;
    int fl = *flag;
    int j = 0;
    while (gid >= a.cum[j + 1]) j++;
    int idx = gid - a.cum[j];
    int kk = idx & 31;
    int n = (idx >> 5) % a.Nc[j];
    int kt = idx / (32 * a.Nc[j]);
    int k = kt * 32 + kk;
    float v = 0.f;
    if (j == 9) {                       // W_out: [256][1], col 0 only
        if (n == 0 && k < a.K[j]) v = rawld(a.src[j], fl, a.soff[j] + k);
    } else if (k < a.K[j]) {
        v = rawld(a.src[j], fl, a.soff[j] + (size_t)k * a.Nc[j] + n);
    }
    a.dst[j][idx] = __float2bfloat16(v);
}

// ---------------- CSR build (hist folded into k_conv_all)
__global__ __launch_bounds__(1024) void k_scan(const int* __restrict__ cnt,
                                               int* __restrict__ off,
                                               int* __restrict__ cur, int N)
{
    __shared__ int sums[1024];
    int tid = threadIdx.x;
    int chunk = (N + 1023) / 1024;
    int base = tid * chunk;
    int s = 0;
    for (int i = 0; i < chunk; i++) { int idx = base + i; if (idx < N) s += cnt[idx]; }
    sums[tid] = s;
    __syncthreads();
    for (int d = 1; d < 1024; d <<= 1) {
        int v = (tid >= d) ? sums[tid - d] : 0;
        __syncthreads();
        sums[tid] += v;
        __syncthreads();
    }
    int run = (tid == 0) ? 0 : sums[tid - 1];
    for (int i = 0; i < chunk; i++) {
        int idx = base + i;
        if (idx < N) { off[idx] = run; cur[idx] = run; run += cnt[idx]; }
    }
    if (tid == 1023) off[N] = run;
}

__global__ __launch_bounds__(256) void k_cscatter(const int* __restrict__ snd,
                                                  int* __restrict__ cur,
                                                  int* __restrict__ eidx, int E)
{
    int e = blockIdx.x * 256 + threadIdx.x;
    if (e >= E) return;
    int p = atomicAdd(&cur[snd[e]], 1);
    eidx[p] = e;
}

// =====================================================================
// Tile kernels (operand-swapped): A-operand = weight frag, B-operand = x frag
// Block = 64 edges x 8 waves (512 thr); wave w owns outcol slice 32w..32w+31
// (4-row x 2-col per-wave tile: measured optimum). Dual LDS buffers
// (71680 B) -> 2 blocks/CU, 16 waves/CU (measured optimum). vv precomputed
// (r5). 2-kt cross-barrier weight prefetch (r12 optimum; 4-kt neutral,
// persistent-tile variant spills to scratch -- r15/r19 post-mortems).
// =====================================================================

// ---------------- MFMA embed tile kernel with fused geometry prologue
__global__ __launch_bounds__(512, 4) void k_embed_mfma(
    const float* __restrict__ vec, const float* __restrict__ na,
    const int* __restrict__ snd, const int* __restrict__ rcv,
    const __hip_bfloat16* __restrict__ We0s, const float* __restrict__ be0,
    const __hip_bfloat16* __restrict__ We1s, const float* __restrict__ be1,
    const __hip_bfloat16* __restrict__ Wv0s, const __hip_bfloat16* __restrict__ Wlws0,
    float* __restrict__ ubuf, float* __restrict__ Ybuf,
    __hip_bfloat16* __restrict__ xb, float* __restrict__ abuf,
    float* __restrict__ wbuf)
{
    __shared__ __align__(16) __hip_bfloat16 As[64 * LROW];  // 37888 B
    __shared__ __align__(16) __hip_bfloat16 Ys[64 * YROW];  // 33792 B
    __shared__ float us[64];
    int tid = threadIdx.x;
    int w = tid >> 6, l = tid & 63;
    int lm = l & 15, lq = l >> 4;
    int eb = blockIdx.x * 64;

    // prefetch GEMM1 weights (both kts) BEFORE the staging barrier
    bf16x8 w0p[2][2];
#pragma unroll
    for (int kt = 0; kt < 2; kt++)
#pragma unroll
        for (int nt = 0; nt < 2; nt++)
            w0p[kt][nt] = *(const bf16x8*)(We0s + ((size_t)(kt * 256 + w * 32 + nt * 16 + lm) * 32 + lq * 8));

    // ---- fused geometry: features straight into As; u,Y to global ----
    {
        int el = tid & 63;
        int part = tid >> 6;
        int ge = eb + el;
        const float SQ2 = 1.41421356237309515f;
        const float PI = 3.14159265358979323846f;
        if (part == 0) {
            float vx = vec[3 * ge + 0], vy = vec[3 * ge + 1], vz = vec[3 * ge + 2];
            float d = sqrtf(vx * vx + vy * vy + vz * vz);
            float d3 = d * d * d;
            float d6 = d3 * d3, d7 = d6 * d, d8 = d7 * d;
            float u = 1.f - 28.f * d6 + 48.f * d7 - 21.f * d8;
            u = (d < 1.f) ? u : 0.f;
            ubuf[ge] = u;
            us[el] = u;
            float invd = __builtin_amdgcn_rcpf(d);
#pragma unroll
            for (int k = 1; k <= 4; k++)
                As[el * LROW + (k - 1)] = __float2bfloat16(SQ2 * __sinf((float)k * PI * d) * invd);
        } else if (part == 4) {
            float vx = vec[3 * ge + 0], vy = vec[3 * ge + 1], vz = vec[3 * ge + 2];
            float d = sqrtf(vx * vx + vy * vy + vz * vz);
            float invd = __builtin_amdgcn_rcpf(d);
#pragma unroll
            for (int k = 5; k <= 8; k++)
                As[el * LROW + (k - 1)] = __float2bfloat16(SQ2 * __sinf((float)k * PI * d) * invd);
        } else if (part == 5) {
#pragma unroll
            for (int j = 40; j < 64; j++) As[el * LROW + j] = __float2bfloat16(0.f);
        } else if (part == 1) {
            int s = snd[ge];
#pragma unroll
            for (int j = 0; j < 16; j++)
                As[el * LROW + 8 + j] = __float2bfloat16(na[(size_t)s * F + j]);
        } else if (part == 2) {
            int r = rcv[ge];
#pragma unroll
            for (int j = 0; j < 16; j++)
                As[el * LROW + 24 + j] = __float2bfloat16(na[(size_t)r * F + j]);
        } else if (part == 3) {
            float vx = vec[3 * ge + 0], vy = vec[3 * ge + 1], vz = vec[3 * ge + 2];
            float d = sqrtf(vx * vx + vy * vy + vz * vz);
            float invd = __builtin_amdgcn_rcpf(d);
            float x = vx * invd, y = vy * invd, z = vz * invd;
            const float s3 = 1.7320508075688772f;
            const float s5 = 2.2360679774997896f;
            const float s15 = 3.8729833462074170f;
            const float s7 = 2.6457513110645907f;
            const float c33 = 2.0916500663351889f;
            const float c32 = 10.246950765959598f;
            const float c31 = 1.6201851746019651f;
            float* Yp = Ybuf + (size_t)ge * 16;
            Yp[0] = 1.f;
            Yp[1] = s3 * x;  Yp[2] = s3 * y;  Yp[3] = s3 * z;
            Yp[4] = s15 * x * y;  Yp[5] = s15 * y * z;
            Yp[6] = 0.5f * s5 * (3.f * z * z - 1.f);
            Yp[7] = s15 * x * z;
            Yp[8] = 0.5f * s15 * (x * x - y * y);
            Yp[9] = c33 * y * (3.f * x * x - y * y);
            Yp[10] = c32 * x * y * z;
            Yp[11] = c31 * y * (5.f * z * z - 1.f);
            Yp[12] = 0.5f * s7 * (5.f * z * z * z - 3.f * z);
            Yp[13] = c31 * x * (5.f * z * z - 1.f);
            Yp[14] = 0.5f * c32 * z * (x * x - y * y);
            Yp[15] = c33 * x * (x * x - 3.f * y * y);
        }
    }
    __syncthreads();

    // GEMM1: [64x64] @ [64x256]  (weights preloaded); wave owns 32 cols
    f32x4 acc[4][2];
#pragma unroll
    for (int mt = 0; mt < 4; mt++)
#pragma unroll
        for (int nt = 0; nt < 2; nt++) acc[mt][nt] = (f32x4){0.f, 0.f, 0.f, 0.f};
#pragma unroll
    for (int kt = 0; kt < 2; kt++) {
#pragma unroll
        for (int mt = 0; mt < 4; mt++) {
            bf16x8 bx = *(const bf16x8*)(As + (mt * 16 + lm) * LROW + kt * 32 + lq * 8);
#pragma unroll
            for (int nt = 0; nt < 2; nt++) acc[mt][nt] = MFMA_B16(w0p[kt][nt], bx, acc[mt][nt]);
        }
    }
    // prefetch GEMM2 kt=0,1 before the Ys barrier
    bf16x8 w1p[2][2];
#pragma unroll
    for (int kt = 0; kt < 2; kt++)
#pragma unroll
        for (int nt = 0; nt < 2; nt++)
            w1p[kt][nt] = *(const bf16x8*)(We1s + ((size_t)(kt * 256 + w * 32 + nt * 16 + lm) * 32 + lq * 8));
    // y0 = silu(acc + b0) -> Ys (disjoint from As: no barrier before writes)
#pragma unroll
    for (int nt = 0; nt < 2; nt++) {
        int cb = w * 32 + nt * 16 + lq * 4;
        f32x4 bb = *(const f32x4*)(be0 + cb);
#pragma unroll
        for (int mt = 0; mt < 4; mt++) {
            int row = mt * 16 + lm;
            bf16x4 v = {f2bs(silu(acc[mt][nt][0] + bb[0])), f2bs(silu(acc[mt][nt][1] + bb[1])),
                        f2bs(silu(acc[mt][nt][2] + bb[2])), f2bs(silu(acc[mt][nt][3] + bb[3]))};
            *(bf16x4*)(Ys + row * YROW + cb) = v;
        }
    }
    __syncthreads();

    // GEMM2: [64x256] @ [256x256]
#pragma unroll
    for (int mt = 0; mt < 4; mt++)
#pragma unroll
        for (int nt = 0; nt < 2; nt++) acc[mt][nt] = (f32x4){0.f, 0.f, 0.f, 0.f};
#pragma unroll
    for (int kt = 0; kt < 8; kt++) {
        bf16x8 aw[2];
#pragma unroll
        for (int nt = 0; nt < 2; nt++)
            aw[nt] = (kt < 2) ? w1p[kt][nt]
                   : *(const bf16x8*)(We1s + ((size_t)(kt * 256 + w * 32 + nt * 16 + lm) * 32 + lq * 8));
#pragma unroll
        for (int mt = 0; mt < 4; mt++) {
            bf16x8 bx = *(const bf16x8*)(Ys + (mt * 16 + lm) * YROW + kt * 32 + lq * 8);
#pragma unroll
            for (int nt = 0; nt < 2; nt++) acc[mt][nt] = MFMA_B16(aw[nt], bx, acc[mt][nt]);
        }
    }
    // prefetch GEMM3 tail weights (2 kts) before epilogue barrier
    const __hip_bfloat16* tw = (w < 4) ? Wv0s : Wlws0;
    bf16x8 twp[2];
#pragma unroll
    for (int kt = 0; kt < 2; kt++)
        twp[kt] = *(const bf16x8*)(tw + ((size_t)(kt * 16 + lm) * 32 + lq * 8));
    // epilogue: x1 = silu(.)*u -> xb global (8B stores) and As
#pragma unroll
    for (int nt = 0; nt < 2; nt++) {
        int cb = w * 32 + nt * 16 + lq * 4;
        f32x4 bb = *(const f32x4*)(be1 + cb);
#pragma unroll
        for (int mt = 0; mt < 4; mt++) {
            int row = mt * 16 + lm;
            float uu = us[row];
            bf16x4 v = {f2bs(silu(acc[mt][nt][0] + bb[0]) * uu),
                        f2bs(silu(acc[mt][nt][1] + bb[1]) * uu),
                        f2bs(silu(acc[mt][nt][2] + bb[2]) * uu),
                        f2bs(silu(acc[mt][nt][3] + bb[3]) * uu)};
            *(bf16x4*)(As + row * LROW + cb) = v;
            *(bf16x4*)(xb + (size_t)(eb + row) * H + cb) = v;
        }
    }
    __syncthreads();

    // GEMM3: a = x@Wv0 (waves 0-3), w = x@Wlw0 (waves 4-7)
    if (w < 4) {
        f32x4 av = (f32x4){0.f, 0.f, 0.f, 0.f};
#pragma unroll
        for (int kt = 0; kt < 8; kt++) {
            bf16x8 bx = *(const bf16x8*)(As + (w * 16 + lm) * LROW + kt * 32 + lq * 8);
            bf16x8 a_v = (kt < 2) ? twp[kt]
                       : *(const bf16x8*)(Wv0s + ((size_t)(kt * 16 + lm) * 32 + lq * 8));
            av = MFMA_B16(a_v, bx, av);
        }
        *(f32x4*)(abuf + (size_t)(eb + w * 16 + lm) * 16 + lq * 4) = av;
    } else {
        int w2 = w - 4;
        f32x4 aw2 = (f32x4){0.f, 0.f, 0.f, 0.f};
#pragma unroll
        for (int kt = 0; kt < 8; kt++) {
            bf16x8 bx = *(const bf16x8*)(As + (w2 * 16 + lm) * LROW + kt * 32 + lq * 8);
            bf16x8 a_w = (kt < 2) ? twp[kt]
                       : *(const bf16x8*)(Wlws0 + ((size_t)(kt * 16 + lm) * 32 + lq * 8));
            aw2 = MFMA_B16(a_w, bx, aw2);
        }
        *(f32x4*)(wbuf + (size_t)(eb + w2 * 16 + lm) * 16 + lq * 4) = aw2;
    }
}

// ---------------- gather #1 (wave-per-node): wYn0 = inv*segsum(w ⊗ Y) AND
// vv0[e,m] = wYn0[s,m,0]*a[e,m].  Wave w owns node 4*bid+w with a PRIVATE
// LDS region; waves march chunk-rounds in lockstep (maxc uniform).
__global__ __launch_bounds__(256) void k_gather0(
    const int* __restrict__ off, const int* __restrict__ eidx,
    const float* __restrict__ wbuf, const float* __restrict__ Ybuf,
    const float* __restrict__ abuf,
    float* __restrict__ wYn0, __hip_bfloat16* __restrict__ vvbuf)
{
    __shared__ float ws[4][16][17];
    __shared__ float Ysh[4][16][17];
    __shared__ float w00s[4][16];
    int tid = threadIdx.x;
    int w = tid >> 6, l = tid & 63;
    int js = l >> 4, i = l & 15;
    int n0 = blockIdx.x * 4;
    int n = n0 + w;
    int beg = off[n], end = off[n + 1];
    int o0 = off[n0], o1 = off[n0 + 1], o2 = off[n0 + 2], o3 = off[n0 + 3], o4 = off[n0 + 4];
    int m01 = max(o1 - o0, o2 - o1), m23 = max(o3 - o2, o4 - o3);
    int maxc = (max(m01, m23) + 15) >> 4;   // uniform across block
    float acc[4] = {0.f, 0.f, 0.f, 0.f};
    for (int r = 0; r < maxc; r++) {
        int c = beg + r * 16;
        int ne = min(16, end - c);          // <=0 when this wave is done
        if (ne > 0) {
#pragma unroll
            for (int k = 0; k < 4; k++) {
                int j = js + 4 * k;
                if (j < ne) {
                    int e = eidx[c + j];
                    ws[w][j][i]  = wbuf[(size_t)e * 16 + i];
                    Ysh[w][j][i] = Ybuf[(size_t)e * 16 + i];
                }
            }
        }
        __syncthreads();
        if (ne > 0) {
            for (int j2 = 0; j2 < ne; j2++) {
                float yv = Ysh[w][j2][i];
#pragma unroll
                for (int k = 0; k < 4; k++)
                    acc[k] += ws[w][j2][js + 4 * k] * yv;
            }
        }
        __syncthreads();
    }
#pragma unroll
    for (int k = 0; k < 4; k++)
        wYn0[(size_t)n * 256 + (js + 4 * k) * 16 + i] = acc[k] * 0.25f;
    if (i == 0) {
#pragma unroll
        for (int k = 0; k < 4; k++) w00s[w][js + 4 * k] = acc[k] * 0.25f;
    }
    __syncthreads();
    // pass 2 (no barriers): vv0[e,i] = w00[i]*a[e,i]; 4 edge-slots per wave
    float w0i = w00s[w][i];
    for (int c = beg + js; c < end; c += 4) {
        int e = eidx[c];
        float a = abuf[(size_t)e * 16 + i];
        vvbuf[(size_t)e * 16 + i] = __float2bfloat16(w0i * a);
    }
}

// ---------------- gather #2 (wave-per-node): wYn1 (local only) AND vv1[e,m] =
// wYn1[s,m,0]*a[e,m]*sum_i wYn0[s,m,i]*Wlsh0[i,0]*Y[e,i].  Also zeroes nacc.
__global__ __launch_bounds__(256) void k_gather1(
    const int* __restrict__ off, const int* __restrict__ eidx,
    const float* __restrict__ wbuf, const float* __restrict__ Ybuf,
    const float* __restrict__ abuf,
    const float* __restrict__ wYn0, const float* __restrict__ Wlsh,
    __hip_bfloat16* __restrict__ vvbuf, float* __restrict__ nacc)
{
    __shared__ float ws[4][16][17];
    __shared__ float Ysh[4][16][17];
    __shared__ float qsh[4][16][17];
    __shared__ float w10s[4][16];
    int tid = threadIdx.x;
    int w = tid >> 6, l = tid & 63;
    int js = l >> 4, i = l & 15;
    int n0 = blockIdx.x * 4;
    int n = n0 + w;
    int beg = off[n], end = off[n + 1];
    if (tid < 4) nacc[n0 + tid] = 0.f;
    int o0 = off[n0], o1 = off[n0 + 1], o2 = off[n0 + 2], o3 = off[n0 + 3], o4 = off[n0 + 4];
    int m01 = max(o1 - o0, o2 - o1), m23 = max(o3 - o2, o4 - o3);
    int maxc = (max(m01, m23) + 15) >> 4;   // uniform across block
    float acc[4] = {0.f, 0.f, 0.f, 0.f};
    for (int r = 0; r < maxc; r++) {
        int c = beg + r * 16;
        int ne = min(16, end - c);
        if (ne > 0) {
#pragma unroll
            for (int k = 0; k < 4; k++) {
                int j = js + 4 * k;
                if (j < ne) {
                    int e = eidx[c + j];
                    ws[w][j][i]  = wbuf[(size_t)e * 16 + i];
                    Ysh[w][j][i] = Ybuf[(size_t)e * 16 + i];
                }
            }
        }
        __syncthreads();
        if (ne > 0) {
            for (int j2 = 0; j2 < ne; j2++) {
                float yv = Ysh[w][j2][i];
#pragma unroll
                for (int k = 0; k < 4; k++)
                    acc[k] += ws[w][j2][js + 4 * k] * yv;
            }
        }
        __syncthreads();
    }
    if (i == 0) {
#pragma unroll
        for (int k = 0; k < 4; k++) w10s[w][js + 4 * k] = acc[k] * 0.25f;
    }
    // qsh[w][m][i] = wYn0[n,m,i] * Wlsh0[i,0]
#pragma unroll
    for (int k = 0; k < 4; k++) {
        int m = js + 4 * k;
        qsh[w][m][i] = wYn0[(size_t)n * 256 + m * 16 + i] * Wlsh[i * 16];
    }
    __syncthreads();
    // pass 2 (no barriers)
    float w1i = w10s[w][i];
    for (int c = beg + js; c < end; c += 4) {
        int e = eidx[c];
        float a = abuf[(size_t)e * 16 + i];
        float t = 0.f;
#pragma unroll
        for (int j = 0; j < 4; j++) {
            f32x4 yv = *(const f32x4*)(Ybuf + (size_t)e * 16 + 4 * j);
            t += qsh[w][i][4 * j + 0] * yv[0] + qsh[w][i][4 * j + 1] * yv[1]
               + qsh[w][i][4 * j + 2] * yv[2] + qsh[w][i][4 * j + 3] * yv[3];
        }
        vvbuf[(size_t)e * 16 + i] = __float2bfloat16(w1i * a * t);
    }
}

// ---------------- MFMA layer tile kernel (operand-swapped, dual buffer,
//                  vv precomputed, 2-kt weight prefetch across barriers)
__global__ __launch_bounds__(512, 4) void k_layer_mfma(
    __hip_bfloat16* __restrict__ xb, const float* __restrict__ ubuf,
    const __hip_bfloat16* __restrict__ vvbuf, const int* __restrict__ rcv,
    const __hip_bfloat16* __restrict__ W1s, const float* __restrict__ b1,
    const __hip_bfloat16* __restrict__ W2s, const float* __restrict__ b2,
    const __hip_bfloat16* __restrict__ Wlwn, float* __restrict__ wbufn,
    const __hip_bfloat16* __restrict__ Wouts, float* __restrict__ nacc,
    int layer)
{
    __shared__ __align__(16) __hip_bfloat16 As[64 * LROW];  // x | vv | 0
    __shared__ __align__(16) __hip_bfloat16 Ys[64 * YROW];  // hidden
    int tid = threadIdx.x;
    int w = tid >> 6, l = tid & 63;
    int lm = l & 15, lq = l >> 4;
    int eb = blockIdx.x * 64;

    // prefetch GEMM1 kt=0,1 BEFORE staging barrier
    bf16x8 w1p[2][2];
#pragma unroll
    for (int kt = 0; kt < 2; kt++)
#pragma unroll
        for (int nt = 0; nt < 2; nt++)
            w1p[kt][nt] = *(const bf16x8*)(W1s + ((size_t)(kt * 256 + w * 32 + nt * 16 + lm) * 32 + lq * 8));

    // stage x tile [64x256] -> As cols 0..256 (512 threads: 4 iters)
#pragma unroll
    for (int i = 0; i < 4; i++) {
        int c = tid + 512 * i;
        int row = c >> 5, kc = c & 31;
        *(bf16x8*)(As + row * LROW + kc * 8) =
            *(const bf16x8*)(xb + (size_t)(eb + row) * H + kc * 8);
    }
    // vv: coalesced 4B/thread from vvbuf; zeros 272..288
    {
        int el = tid & 63;
        int mh = (tid >> 6) * 2;     // 8 groups x 2 m each
        int ge = eb + el;
        *(unsigned int*)(As + el * LROW + 256 + mh) =
            *(const unsigned int*)((const short*)vvbuf + (size_t)ge * 16 + mh);
        if (tid < 64) {
#pragma unroll
            for (int j = 0; j < 16; j++) As[tid * LROW + 272 + j] = __float2bfloat16(0.f);
        }
    }
    __syncthreads();

    float uu[4];
#pragma unroll
    for (int mt = 0; mt < 4; mt++) uu[mt] = ubuf[eb + mt * 16 + lm];

    // GEMM1: [64x288] @ [288x256]; wave owns 32 output cols
    f32x4 acc[4][2];
#pragma unroll
    for (int mt = 0; mt < 4; mt++)
#pragma unroll
        for (int nt = 0; nt < 2; nt++) acc[mt][nt] = (f32x4){0.f, 0.f, 0.f, 0.f};
#pragma unroll
    for (int kt = 0; kt < 9; kt++) {
        bf16x8 aw[2];
#pragma unroll
        for (int nt = 0; nt < 2; nt++)
            aw[nt] = (kt < 2) ? w1p[kt][nt]
                   : *(const bf16x8*)(W1s + ((size_t)(kt * 256 + w * 32 + nt * 16 + lm) * 32 + lq * 8));
#pragma unroll
        for (int mt = 0; mt < 4; mt++) {
            bf16x8 bx = *(const bf16x8*)(As + (mt * 16 + lm) * LROW + kt * 32 + lq * 8);
#pragma unroll
            for (int nt = 0; nt < 2; nt++) acc[mt][nt] = MFMA_B16(aw[nt], bx, acc[mt][nt]);
        }
    }
    // prefetch GEMM2 kt=0,1 before the Ys barrier
    bf16x8 w2p[2][2];
#pragma unroll
    for (int kt = 0; kt < 2; kt++)
#pragma unroll
        for (int nt = 0; nt < 2; nt++)
            w2p[kt][nt] = *(const bf16x8*)(W2s + ((size_t)(kt * 256 + w * 32 + nt * 16 + lm) * 32 + lq * 8));
    // y1 = silu(acc + b1) -> Ys packed (disjoint from As)
#pragma unroll
    for (int nt = 0; nt < 2; nt++) {
        int cb = w * 32 + nt * 16 + lq * 4;
        f32x4 bb = *(const f32x4*)(b1 + cb);
#pragma unroll
        for (int mt = 0; mt < 4; mt++) {
            int row = mt * 16 + lm;
            bf16x4 v = {f2bs(silu(acc[mt][nt][0] + bb[0])), f2bs(silu(acc[mt][nt][1] + bb[1])),
                        f2bs(silu(acc[mt][nt][2] + bb[2])), f2bs(silu(acc[mt][nt][3] + bb[3]))};
            *(bf16x4*)(Ys + row * YROW + cb) = v;
        }
    }
    __syncthreads();

    // GEMM2: [64x256] @ [256x256]
#pragma unroll
    for (int mt = 0; mt < 4; mt++)
#pragma unroll
        for (int nt = 0; nt < 2; nt++) acc[mt][nt] = (f32x4){0.f, 0.f, 0.f, 0.f};
#pragma unroll
    for (int kt = 0; kt < 8; kt++) {
        bf16x8 aw[2];
#pragma unroll
        for (int nt = 0; nt < 2; nt++)
            aw[nt] = (kt < 2) ? w2p[kt][nt]
                   : *(const bf16x8*)(W2s + ((size_t)(kt * 256 + w * 32 + nt * 16 + lm) * 32 + lq * 8));
#pragma unroll
        for (int mt = 0; mt < 4; mt++) {
            bf16x8 bx = *(const bf16x8*)(Ys + (mt * 16 + lm) * YROW + kt * 32 + lq * 8);
#pragma unroll
            for (int nt = 0; nt < 2; nt++) acc[mt][nt] = MFMA_B16(aw[nt], bx, acc[mt][nt]);
        }
    }
    // prefetch tail weights (2 kts) before epilogue barrier (waves 0-3 only use them)
    const __hip_bfloat16* tw = (layer == 0) ? Wlwn : Wouts;
    bf16x8 twp[2];
#pragma unroll
    for (int kt = 0; kt < 2; kt++)
        twp[kt] = *(const bf16x8*)(tw + ((size_t)(kt * 16 + lm) * 32 + lq * 8));
    // epilogue: xnew = (x_old + u*silu(acc+b2))/sqrt2; x_old read b64 from As;
    // same thread writes same cells (WAR-safe, no barrier).
    const float rs2 = 0.70710678118654752f;
#pragma unroll
    for (int nt = 0; nt < 2; nt++) {
        int cb = w * 32 + nt * 16 + lq * 4;
        f32x4 bb = *(const f32x4*)(b2 + cb);
#pragma unroll
        for (int mt = 0; mt < 4; mt++) {
            int row = mt * 16 + lm;
            bf16x4 xo = *(const bf16x4*)(As + row * LROW + cb);
            bf16x4 v;
#pragma unroll
            for (int r = 0; r < 4; r++) {
                float xn = (bs2f(xo[r]) + uu[mt] * silu(acc[mt][nt][r] + bb[r])) * rs2;
                v[r] = f2bs(xn);
            }
            *(bf16x4*)(As + row * LROW + cb) = v;
            if (layer == 0) *(bf16x4*)(xb + (size_t)(eb + row) * H + cb) = v;
        }
    }
    __syncthreads();

    if (layer == 0) {
        // wcomp: w = x_new @ Wlwn -- waves 0-3 own edges w*16..w*16+15
        if (w < 4) {
            f32x4 cw = (f32x4){0.f, 0.f, 0.f, 0.f};
#pragma unroll
            for (int kt = 0; kt < 8; kt++) {
                bf16x8 bx = *(const bf16x8*)(As + (w * 16 + lm) * LROW + kt * 32 + lq * 8);
                bf16x8 a = (kt < 2) ? twp[kt]
                         : *(const bf16x8*)(Wlwn + ((size_t)(kt * 16 + lm) * 32 + lq * 8));
                cw = MFMA_B16(a, bx, cw);
            }
            *(f32x4*)(wbufn + (size_t)(eb + w * 16 + lm) * 16 + lq * 4) = cw;
        }
    } else {
        // out-proj: edge_out = (x_new @ W_out) * u -> atomicAdd nacc[rcv]
        if (w < 4) {
            f32x4 co = (f32x4){0.f, 0.f, 0.f, 0.f};
#pragma unroll
            for (int kt = 0; kt < 8; kt++) {
                bf16x8 bx = *(const bf16x8*)(As + (w * 16 + lm) * LROW + kt * 32 + lq * 8);
                bf16x8 a = (kt < 2) ? twp[kt]
                         : *(const bf16x8*)(Wouts + ((size_t)(kt * 16 + lm) * 32 + lq * 8));
                co = MFMA_B16(a, bx, co);
            }
            if (lq == 0) {
                int e = eb + w * 16 + lm;
                atomicAdd(&nacc[rcv[e]], co[0] * ubuf[e]);
            }
        }
    }
}

__global__ __launch_bounds__(256) void k_final(
    const float* __restrict__ nacc, void* __restrict__ out, const int* __restrict__ flag,
    float inv, int N)
{
    int n = blockIdx.x * 256 + threadIdx.x;
    if (n >= N) return;
    float v = nacc[n] * inv;
    if (*flag) ((float*)out)[n] = v;
    else       ((__hip_bfloat16*)out)[n] = __float2bfloat16(v);
}

extern "C" void kernel_launch(void* const* d_in, const int* in_sizes, int n_in,
                              void* d_out, int out_size, void* d_ws, size_t ws_size,
                              hipStream_t stream)
{
    const int E = in_sizes[2];      // 131072
    const int N = in_sizes[0] / F;  // 8192
    (void)n_in; (void)ws_size; (void)out_size;

    char* wsb = (char*)d_ws;
    size_t off = 0;
    int* flag = (int*)wsb; off += 256;

    // canonical fp32 only for fp32-consumers: na, vec, be0, be1, Wlsh, bly1, bly2
    const int cidx[7] = {0, 1, 5, 7, 10, 12, 14};
    float* canon[7];
    for (int k = 0; k < 7; k++) {
        canon[k] = (float*)(wsb + off);
        off += (size_t)in_sizes[cidx[k]] * 4;
        off = (off + 255) & ~(size_t)255;
    }
    const float* naC   = canon[0];
    const float* vecC  = canon[1];
    const float* be0C  = canon[2];
    const float* be1C  = canon[3];
    const float* WlshC = canon[4];
    const float* bly1C = canon[5];
    const float* bly2C = canon[6];

    // swizzled bf16 weights
    __hip_bfloat16* We0s  = (__hip_bfloat16*)(wsb + off); off += 64 * 256 * 2;
    __hip_bfloat16* We1s  = (__hip_bfloat16*)(wsb + off); off += 256 * 256 * 2;
    __hip_bfloat16* Wv0s  = (__hip_bfloat16*)(wsb + off); off += 256 * 16 * 2;
    __hip_bfloat16* Wlws0 = (__hip_bfloat16*)(wsb + off); off += 256 * 16 * 2;
    __hip_bfloat16* Wlws1 = (__hip_bfloat16*)(wsb + off); off += 256 * 16 * 2;
    __hip_bfloat16* W1s0  = (__hip_bfloat16*)(wsb + off); off += 288 * 256 * 2;
    __hip_bfloat16* W1s1  = (__hip_bfloat16*)(wsb + off); off += 288 * 256 * 2;
    __hip_bfloat16* W2s0  = (__hip_bfloat16*)(wsb + off); off += 256 * 256 * 2;
    __hip_bfloat16* W2s1  = (__hip_bfloat16*)(wsb + off); off += 256 * 256 * 2;
    __hip_bfloat16* Wouts = (__hip_bfloat16*)(wsb + off); off += 256 * 16 * 2;
    off = (off + 255) & ~(size_t)255;

    __hip_bfloat16* xbuf = (__hip_bfloat16*)(wsb + off); off += (size_t)E * H * 2;
    float* wYn0 = (float*)(wsb + off); off += (size_t)N * H * 4;
    __hip_bfloat16* vvbuf = (__hip_bfloat16*)(wsb + off); off += (size_t)E * 16 * 2;
    float* ubuf = (float*)(wsb + off); off += (size_t)E * 4;
    float* Ybuf = (float*)(wsb + off); off += (size_t)E * 16 * 4;
    float* abuf = (float*)(wsb + off); off += (size_t)E * 16 * 4;
    float* wbuf = (float*)(wsb + off); off += (size_t)E * 16 * 4;
    float* nacc = (float*)(wsb + off); off += (size_t)N * 4;
    int* cnt  = (int*)(wsb + off); off += (size_t)N * 4;
    int* offb = (int*)(wsb + off); off += (size_t)(N + 1) * 4;
    int* cur  = (int*)(wsb + off); off += (size_t)N * 4;
    int* eidx = (int*)(wsb + off); off += (size_t)E * 4;

    const int* snd = (const int*)d_in[2];
    const int* rcv = (const int*)d_in[3];
    const float inv = 0.25f;
    const int nb64 = E / 64;

    // dtype sniff (+ cnt zeroing) + merged canonicalization (+ sender hist)
    k_sniff<<<1, 256, 0, stream>>>(d_in[1], flag, cnt, N);
    {
        ConvArgs ca;
        int c = 0;
        for (int k = 0; k < 7; k++) {
            ca.src[k] = d_in[cidx[k]];
            ca.dst[k] = canon[k];
            ca.cum[k] = c;
            c += in_sizes[cidx[k]];
        }
        ca.cum[7] = c;
        k_conv_all<<<(c + 255) / 256, 256, 0, stream>>>(ca, flag, snd, cnt, E);
    }

    // merged weight swizzles (direct from RAW input; entry 9 = W_out mode)
    {
        SwzArgs sa;
        const void* srcs[10] = {d_in[4], d_in[6], d_in[8], d_in[9], d_in[9],
                                d_in[11], d_in[11], d_in[13], d_in[13], d_in[15]};
        size_t soffs[10]     = {0, 0, 0, 0, 256 * 16,
                                0, 272 * 256, 0, 256 * 256, 0};
        __hip_bfloat16* dsts[10] = {We0s, We1s, Wv0s, Wlws0, Wlws1,
                                    W1s0, W1s1, W2s0, W2s1, Wouts};
        int Ks[10]    = {40, 256, 256, 256, 256, 272, 272, 256, 256, 256};
        int Ncs[10]   = {256, 256, 16, 16, 16, 256, 256, 256, 256, 16};
        int Kpads[10] = {64, 256, 256, 256, 256, 288, 288, 256, 256, 256};
        int c = 0;
        for (int j = 0; j < 10; j++) {
            sa.src[j] = srcs[j]; sa.dst[j] = dsts[j];
            sa.K[j] = Ks[j]; sa.Nc[j] = Ncs[j]; sa.soff[j] = soffs[j];
            sa.cum[j] = c;
            c += (Kpads[j] >> 5) * Ncs[j] * 32;
        }
        sa.cum[10] = c;
        k_swz_all<<<(c + 255) / 256, 256, 0, stream>>>(sa, flag);
    }

    // sender CSR (hist folded into conv)
    k_scan<<<1, 1024, 0, stream>>>(cnt, offb, cur, N);
    k_cscatter<<<(E + 255) / 256, 256, 0, stream>>>(snd, cur, eidx, E);

    // embed (fused geometry)
    k_embed_mfma<<<nb64, 512, 0, stream>>>(vecC, naC, snd, rcv,
                                           We0s, be0C, We1s, be1C, Wv0s, Wlws0,
                                           ubuf, Ybuf, xbuf, abuf, wbuf);

    // layer 0: gather0 emits wYn0 + vv0; layer kernel emits w for layer 1
    k_gather0<<<N / 4, 256, 0, stream>>>(offb, eidx, wbuf, Ybuf, abuf, wYn0, vvbuf);
    k_layer_mfma<<<nb64, 512, 0, stream>>>(xbuf, ubuf, vvbuf, rcv,
                                           W1s0, bly1C, W2s0, bly2C,
                                           Wlws1, wbuf,
                                           (const __hip_bfloat16*)nullptr, (float*)nullptr, 0);
    // layer 1: gather1 emits vv1 (wYn1 kept local) + zeroes nacc; fused
    // out-proj -> nacc
    k_gather1<<<N / 4, 256, 0, stream>>>(offb, eidx, wbuf, Ybuf, abuf, wYn0, WlshC,
                                         vvbuf, nacc);
    k_layer_mfma<<<nb64, 512, 0, stream>>>(xbuf, ubuf, vvbuf, rcv,
                                           W1s1, bly1C + H, W2s1, bly2C + H,
                                           (const __hip_bfloat16*)nullptr, (float*)nullptr,
                                           Wouts, nacc, 1);

    k_final<<<(N + 255) / 256, 256, 0, stream>>>(nacc, d_out, flag, inv, N);
}